// Round 1
// baseline (2738.386 us; speedup 1.0000x reference)
//
#include <hip/hip_runtime.h>
#include <hip/hip_bf16.h>
#include <math.h>

#define NB 8
#define NIN 3136
#define NOUT 784
#define DIN 96
#define DOUT 192
#define HID 384
#define TOK_IN (NB*NIN)    // 25088
#define TOK_OUT (NB*NOUT)  // 6272

// ---------------- generic LayerNorm over last dim (D<=192), one row per block (64 thr)
__global__ __launch_bounds__(64) void k_ln(const float* __restrict__ in, float* __restrict__ out,
                                           const float* __restrict__ g, const float* __restrict__ bb,
                                           int D) {
  int row = blockIdx.x;
  const float* ip = in + (size_t)row * D;
  float* op = out + (size_t)row * D;
  int t = threadIdx.x;
  float v0 = 0.f, v1 = 0.f, v2 = 0.f, s = 0.f, sq = 0.f;
  if (t < D)       { v0 = ip[t];       s += v0; sq += v0*v0; }
  if (t + 64 < D)  { v1 = ip[t+64];    s += v1; sq += v1*v1; }
  if (t + 128 < D) { v2 = ip[t+128];   s += v2; sq += v2*v2; }
  #pragma unroll
  for (int off = 32; off; off >>= 1) { s += __shfl_xor(s, off); sq += __shfl_xor(sq, off); }
  float mu = s / (float)D;
  float var = sq / (float)D - mu*mu;
  float rs = rsqrtf(var + 1e-5f);
  if (t < D)       op[t]     = (v0-mu)*rs*g[t]     + bb[t];
  if (t + 64 < D)  op[t+64]  = (v1-mu)*rs*g[t+64]  + bb[t+64];
  if (t + 128 < D) op[t+128] = (v2-mu)*rs*g[t+128] + bb[t+128];
}

// ---------------- weight transposes (once per launch)
__global__ void k_tr(const float* __restrict__ cw, const float* __restrict__ kw,
                     const float* __restrict__ vw, const float* __restrict__ qw,
                     const float* __restrict__ w1, const float* __restrict__ w2,
                     float* __restrict__ wct, float* __restrict__ wkvT, float* __restrict__ qwT,
                     float* __restrict__ w1T, float* __restrict__ w2T) {
  int i = blockIdx.x * 256 + threadIdx.x;
  if (i < 165888) {                               // wct[kh][ci][kw][co]
    int co = i % 192; int t1 = i / 192;
    int kwi = t1 % 3; int t2 = t1 / 3;
    int ci = t2 % 96; int kh = t2 / 96;
    wct[i] = cw[((co*96 + ci)*3 + kh)*3 + kwi];
  } else if (i < 165888 + 27648) {                // wkvT[e][288] : k|v
    int j = i - 165888; int o = j % 288; int e = j / 288;
    wkvT[j] = (o < 96) ? kw[o*96 + e] : vw[(o-96)*96 + e];
  } else if (i < 165888 + 27648 + 18432) {        // qwT[e][96]
    int j = i - 165888 - 27648; int o = j % 96; int e = j / 96;
    qwT[j] = qw[o*192 + e];
  } else if (i < 165888 + 27648 + 18432 + 73728) {// w1T[e][384]
    int j = i - 165888 - 27648 - 18432; int hh = j % 384; int e = j / 384;
    w1T[j] = w1[hh*192 + e];
  } else if (i < 165888 + 27648 + 18432 + 73728 + 73728) { // w2T[h][192]
    int j = i - 165888 - 27648 - 18432 - 73728; int o = j % 192; int h = j / 192;
    w2T[j] = w2[o*384 + h];
  }
}

// ---------------- strided 3x3 conv seed. block=(ho,b), 192 thr: t->(wo_half, co pair)
__global__ __launch_bounds__(192) void k_conv(const float* __restrict__ x,
                                              const float* __restrict__ wct,
                                              float* __restrict__ seed) {
  int ho = blockIdx.x, b = blockIdx.y;
  int t = threadIdx.x;
  int wo_half = t / 96, cb = t % 96;
  int co0 = cb*2, wo0 = wo_half*14;
  float acc0[14], acc1[14];
  #pragma unroll
  for (int i = 0; i < 14; i++) { acc0[i] = 0.f; acc1[i] = 0.f; }
  for (int ci4 = 0; ci4 < 24; ci4++) {
    int ci0 = ci4*4;
    #pragma unroll
    for (int kh = 0; kh < 3; kh++) {
      int h = 2*ho - 1 + kh;
      float xc[29][4];
      #pragma unroll
      for (int cc = 0; cc < 29; cc++) {
        int wx = 2*wo0 + cc - 1;
        float4 val = make_float4(0.f,0.f,0.f,0.f);
        if (h >= 0 && wx >= 0)
          val = *(const float4*)(x + (((size_t)b*NIN + h*56 + wx)*DIN + ci0));
        xc[cc][0]=val.x; xc[cc][1]=val.y; xc[cc][2]=val.z; xc[cc][3]=val.w;
      }
      float2 wv[4][3];
      #pragma unroll
      for (int j = 0; j < 4; j++)
        #pragma unroll
        for (int kw = 0; kw < 3; kw++)
          wv[j][kw] = *(const float2*)(wct + (((size_t)(kh*96 + ci0 + j)*3 + kw)*192 + co0));
      #pragma unroll
      for (int j = 0; j < 4; j++)
        #pragma unroll
        for (int kw = 0; kw < 3; kw++)
          #pragma unroll
          for (int wo = 0; wo < 14; wo++) {
            float xv = xc[2*wo + kw][j];
            acc0[wo] += xv * wv[j][kw].x;
            acc1[wo] += xv * wv[j][kw].y;
          }
    }
  }
  #pragma unroll
  for (int wo = 0; wo < 14; wo++) {
    float2 o2 = make_float2(acc0[wo], acc1[wo]);
    *(float2*)(seed + (((size_t)b*NOUT + ho*28 + wo0 + wo)*DOUT + co0)) = o2;
  }
}

// ---------------- kv = xn @ [k_w|v_w]^T. block=32 tokens, 256 thr (32 olane x 8 tg), TM=4 TN=9
__global__ __launch_bounds__(256) void k_kv(const float* __restrict__ xn,
                                            const float* __restrict__ wkvT,
                                            float* __restrict__ kvb) {
  __shared__ float xt[32][98];
  int tok0 = blockIdx.x * 32;
  int t = threadIdx.x;
  for (int i = t; i < 32*DIN; i += 256) {
    int tok = i / DIN, e = i % DIN;
    xt[tok][e] = xn[(size_t)(tok0 + tok)*DIN + e];
  }
  __syncthreads();
  int ol = t & 31, tg = t >> 5;
  float acc[4][9];
  #pragma unroll
  for (int i = 0; i < 4; i++)
    #pragma unroll
    for (int j = 0; j < 9; j++) acc[i][j] = 0.f;
  for (int e = 0; e < DIN; e++) {
    float x0 = xt[tg*4+0][e], x1 = xt[tg*4+1][e], x2 = xt[tg*4+2][e], x3 = xt[tg*4+3][e];
    const float* wp = wkvT + (size_t)e*288 + ol;
    #pragma unroll
    for (int j = 0; j < 9; j++) {
      float wv = wp[32*j];
      acc[0][j] += x0*wv; acc[1][j] += x1*wv; acc[2][j] += x2*wv; acc[3][j] += x3*wv;
    }
  }
  #pragma unroll
  for (int i = 0; i < 4; i++)
    #pragma unroll
    for (int j = 0; j < 9; j++)
      kvb[(size_t)(tok0 + tg*4 + i)*288 + ol + 32*j] = acc[i][j];
}

// ---------------- q = LN(x_out) @ q_w^T. block=32 tokens, TM=4 TN=3
__global__ __launch_bounds__(256) void k_q(const float* __restrict__ xqn,
                                           const float* __restrict__ qwT,
                                           float* __restrict__ qb) {
  __shared__ float xt[32][194];
  int tok0 = blockIdx.x * 32;
  int t = threadIdx.x;
  for (int i = t; i < 32*DOUT; i += 256) {
    int tok = i / DOUT, e = i % DOUT;
    xt[tok][e] = xqn[(size_t)(tok0 + tok)*DOUT + e];
  }
  __syncthreads();
  int ol = t & 31, tg = t >> 5;
  float acc[4][3];
  #pragma unroll
  for (int i = 0; i < 4; i++) { acc[i][0]=0.f; acc[i][1]=0.f; acc[i][2]=0.f; }
  for (int e = 0; e < DOUT; e++) {
    float x0 = xt[tg*4+0][e], x1 = xt[tg*4+1][e], x2 = xt[tg*4+2][e], x3 = xt[tg*4+3][e];
    const float* wp = qwT + (size_t)e*DIN + ol;
    #pragma unroll
    for (int j = 0; j < 3; j++) {
      float wv = wp[32*j];
      acc[0][j] += x0*wv; acc[1][j] += x1*wv; acc[2][j] += x2*wv; acc[3][j] += x3*wv;
    }
  }
  #pragma unroll
  for (int i = 0; i < 4; i++)
    #pragma unroll
    for (int j = 0; j < 3; j++)
      qb[(size_t)(tok0 + tg*4 + i)*DIN + ol + 32*j] = acc[i][j];
}

// ---------------- window helper: 9 candidate slots + duplicate mask (all constant-indexed)
__device__ __forceinline__ void window9(int n, int* ms, bool* dup) {
  int r = n / 56, c = n % 56;
  int rb = r >> 1, cb = c >> 1;
  #pragma unroll
  for (int j = 0; j < 9; j++) {
    int ro = rb + (j/3) - 1; ro = ro < 0 ? 0 : (ro > 27 ? 27 : ro);
    int co = cb + (j%3) - 1; co = co < 0 ? 0 : (co > 27 ? 27 : co);
    ms[j] = ro*28 + co;
  }
  #pragma unroll
  for (int j = 0; j < 9; j++) {
    bool d = false;
    #pragma unroll
    for (int i = 0; i < j; i++) d = d || (ms[i] == ms[j]);
    dup[j] = d;
  }
}

// ---------------- sparse logits + softmax + a_ups + colsum. one wave per (b,n)
__global__ __launch_bounds__(256) void k_attn1(const float* __restrict__ kvb,
                                               const float* __restrict__ qb,
                                               const float* __restrict__ tau,
                                               const float* __restrict__ rpb,
                                               const int* __restrict__ qidx,
                                               float* __restrict__ aups,
                                               float* __restrict__ colsum) {
  int wid = blockIdx.x * 4 + (threadIdx.x >> 6);
  int l = threadIdx.x & 63;
  int b = wid / NIN, n = wid % NIN;
  int ms[9]; bool dup[9];
  window9(n, ms, dup);
  const float* kp = kvb + (size_t)wid * 288;
  float k0 = kp[l];
  float k1 = (l < 32) ? kp[64 + l] : 0.0f;
  float et = expf(tau[0]);
  float lg[9];
  #pragma unroll
  for (int j = 0; j < 9; j++) {
    float d = -1e30f;
    if (!dup[j]) {
      const float* qp = qb + (size_t)(b*NOUT + ms[j]) * DIN;
      float p = k0 * qp[l];
      if (l < 32) p += k1 * qp[64 + l];
      #pragma unroll
      for (int off = 32; off; off >>= 1) p += __shfl_xor(p, off);
      d = p * et + rpb[qidx[(size_t)n*NOUT + ms[j]]];
    }
    lg[j] = d;
  }
  float mx = lg[0];
  #pragma unroll
  for (int j = 1; j < 9; j++) mx = fmaxf(mx, lg[j]);
  float s = 0.f, ex[9];
  #pragma unroll
  for (int j = 0; j < 9; j++) { ex[j] = dup[j] ? 0.f : expf(lg[j] - mx); s += ex[j]; }
  float inv = 1.0f / s;
  #pragma unroll
  for (int j = 0; j < 9; j++) {
    if (l == j && !dup[j]) {
      float a = ex[j] * inv;
      aups[(size_t)wid*NOUT + ms[j]] = a;
      atomicAdd(&colsum[b*NOUT + ms[j]], a);
    }
  }
}

// ---------------- a_down (final iteration only): thread per (b,n)
__global__ __launch_bounds__(256) void k_attn2(const float* __restrict__ aups,
                                               const float* __restrict__ colsum,
                                               float* __restrict__ adown) {
  int id = blockIdx.x * 256 + threadIdx.x;
  int b = id / NIN, n = id % NIN;
  int ms[9]; bool dup[9];
  window9(n, ms, dup);
  #pragma unroll
  for (int j = 0; j < 9; j++) {
    if (!dup[j]) {
      size_t idx = (size_t)id*NOUT + ms[j];
      adown[idx] = aups[idx] / (colsum[b*NOUT + ms[j]] + 1e-8f);
    }
  }
}

// ---------------- updates gather + LN + residual. block = (b, 2x2 slot tile), 192 thr
__global__ __launch_bounds__(192) void k_upd(const float* __restrict__ aups,
                                             const float* __restrict__ colsum,
                                             const float* __restrict__ kvb,
                                             float* __restrict__ xout,
                                             const float* __restrict__ g,
                                             const float* __restrict__ bb) {
  __shared__ float avals[4][64];
  __shared__ float red[4][3][2];
  __shared__ float bc[4][2];
  int b = blockIdx.z;
  int ro0 = blockIdx.y*2, co0 = blockIdx.x*2;
  int r0 = 2*ro0 - 2; if (r0 < 0) r0 = 0;
  int r1 = 2*ro0 + 5; if (r1 > 55) r1 = 55;
  int c0 = 2*co0 - 2; if (c0 < 0) c0 = 0;
  int c1 = 2*co0 + 5; if (c1 > 55) c1 = 55;
  int nr = r1 - r0 + 1, nc = c1 - c0 + 1, cnt = nr*nc;
  int t = threadIdx.x;
  int m0 = ro0*28 + co0, m1 = m0+1, m2 = m0+28, m3 = m0+29;
  if (t < cnt) {
    int ri = t / nc, ci = t % nc;
    int n = (r0 + ri)*56 + (c0 + ci);
    const float* ap = aups + ((size_t)b*NIN + n)*NOUT;
    avals[0][t] = ap[m0]; avals[1][t] = ap[m1];
    avals[2][t] = ap[m2]; avals[3][t] = ap[m3];
  }
  __syncthreads();
  float a0=0.f, a1=0.f, a2=0.f, a3=0.f;
  int i = 0;
  for (int ri = 0; ri < nr; ri++) {
    int nbase = (r0 + ri)*56 + c0;
    for (int ci = 0; ci < nc; ci++, i++) {
      float vv = kvb[((size_t)b*NIN + nbase + ci)*288 + 96 + t];
      a0 += avals[0][i]*vv; a1 += avals[1][i]*vv;
      a2 += avals[2][i]*vv; a3 += avals[3][i]*vv;
    }
  }
  a0 *= 1.0f/(colsum[b*NOUT+m0]+1e-8f);
  a1 *= 1.0f/(colsum[b*NOUT+m1]+1e-8f);
  a2 *= 1.0f/(colsum[b*NOUT+m2]+1e-8f);
  a3 *= 1.0f/(colsum[b*NOUT+m3]+1e-8f);
  float s0=a0,s1=a1,s2=a2,s3=a3, q0=a0*a0,q1=a1*a1,q2=a2*a2,q3=a3*a3;
  #pragma unroll
  for (int off = 32; off; off >>= 1) {
    s0 += __shfl_xor(s0, off); q0 += __shfl_xor(q0, off);
    s1 += __shfl_xor(s1, off); q1 += __shfl_xor(q1, off);
    s2 += __shfl_xor(s2, off); q2 += __shfl_xor(q2, off);
    s3 += __shfl_xor(s3, off); q3 += __shfl_xor(q3, off);
  }
  int w = t >> 6, l = t & 63;
  if (l == 0) {
    red[0][w][0]=s0; red[0][w][1]=q0;
    red[1][w][0]=s1; red[1][w][1]=q1;
    red[2][w][0]=s2; red[2][w][1]=q2;
    red[3][w][0]=s3; red[3][w][1]=q3;
  }
  __syncthreads();
  if (t < 4) {
    float S = red[t][0][0]+red[t][1][0]+red[t][2][0];
    float Q = red[t][0][1]+red[t][1][1]+red[t][2][1];
    float mu = S * (1.0f/192.0f);
    float var = Q * (1.0f/192.0f) - mu*mu;
    bc[t][0] = mu; bc[t][1] = rsqrtf(var + 1e-5f);
  }
  __syncthreads();
  float gt = g[t], bt = bb[t];
  xout[((size_t)b*NOUT+m0)*DOUT + t] += (a0-bc[0][0])*bc[0][1]*gt + bt;
  xout[((size_t)b*NOUT+m1)*DOUT + t] += (a1-bc[1][0])*bc[1][1]*gt + bt;
  xout[((size_t)b*NOUT+m2)*DOUT + t] += (a2-bc[2][0])*bc[2][1]*gt + bt;
  xout[((size_t)b*NOUT+m3)*DOUT + t] += (a3-bc[3][0])*bc[3][1]*gt + bt;
}

// ---------------- MLP + LN + residual. block = 32 tokens, 256 thr
__global__ __launch_bounds__(256) void k_mlp(float* __restrict__ xout,
                                             const float* __restrict__ w1T, const float* __restrict__ b1,
                                             const float* __restrict__ w2T, const float* __restrict__ b2,
                                             const float* __restrict__ g, const float* __restrict__ bb,
                                             float* __restrict__ dout, int write_out) {
  __shared__ float xt[32][194];
  __shared__ float ht[32][386];
  int tok0 = blockIdx.x * 32;
  int t = threadIdx.x;
  for (int idx = t; idx < 32*DOUT; idx += 256) {
    int tok = idx / DOUT, e = idx % DOUT;
    xt[tok][e] = xout[(size_t)(tok0 + tok)*DOUT + e];
  }
  __syncthreads();
  int ol = t & 31, tg = t >> 5;
  float acc[4][12];
  #pragma unroll
  for (int i = 0; i < 4; i++)
    #pragma unroll
    for (int j = 0; j < 12; j++) acc[i][j] = 0.f;
  for (int e = 0; e < DOUT; e++) {
    float x0 = xt[tg*4+0][e], x1 = xt[tg*4+1][e], x2 = xt[tg*4+2][e], x3 = xt[tg*4+3][e];
    const float* wp = w1T + (size_t)e*HID + ol;
    #pragma unroll
    for (int j = 0; j < 12; j++) {
      float wv = wp[32*j];
      acc[0][j] += x0*wv; acc[1][j] += x1*wv; acc[2][j] += x2*wv; acc[3][j] += x3*wv;
    }
  }
  #pragma unroll
  for (int j = 0; j < 12; j++) {
    int hh = ol + 32*j;
    float bv = b1[hh];
    #pragma unroll
    for (int i = 0; i < 4; i++) {
      float v = acc[i][j] + bv;
      v = 0.5f*v*(1.0f + erff(v*0.70710678118f));
      ht[tg*4+i][hh] = v;
    }
  }
  __syncthreads();
  float o2[4][6];
  #pragma unroll
  for (int i = 0; i < 4; i++)
    #pragma unroll
    for (int j = 0; j < 6; j++) o2[i][j] = 0.f;
  for (int h = 0; h < HID; h++) {
    float x0 = ht[tg*4+0][h], x1 = ht[tg*4+1][h], x2 = ht[tg*4+2][h], x3 = ht[tg*4+3][h];
    const float* wp = w2T + (size_t)h*DOUT + ol;
    #pragma unroll
    for (int j = 0; j < 6; j++) {
      float wv = wp[32*j];
      o2[0][j] += x0*wv; o2[1][j] += x1*wv; o2[2][j] += x2*wv; o2[3][j] += x3*wv;
    }
  }
  __syncthreads();
  float (*ot)[194] = (float(*)[194])ht;   // reuse h LDS for the out tile
  #pragma unroll
  for (int j = 0; j < 6; j++) {
    int o = ol + 32*j;
    float bv = b2[o];
    #pragma unroll
    for (int i = 0; i < 4; i++) ot[tg*4+i][o] = o2[i][j] + bv;
  }
  __syncthreads();
  int tok = t >> 3, l8 = t & 7;
  float s = 0.f, sq = 0.f;
  for (int e = l8; e < DOUT; e += 8) { float v = ot[tok][e]; s += v; sq += v*v; }
  #pragma unroll
  for (int off = 4; off; off >>= 1) { s += __shfl_xor(s, off, 8); sq += __shfl_xor(sq, off, 8); }
  float mu = s * (1.f/192.f);
  float var = sq * (1.f/192.f) - mu*mu;
  float rs = rsqrtf(var + 1e-5f);
  for (int e = l8; e < DOUT; e += 8) {
    float v = (ot[tok][e] - mu)*rs*g[e] + bb[e];
    float nx = xt[tok][e] + v;
    size_t gi = (size_t)(tok0 + tok)*DOUT + e;
    xout[gi] = nx;
    if (write_out) dout[gi] = nx;
  }
}

extern "C" void kernel_launch(void* const* d_in, const int* in_sizes, int n_in,
                              void* d_out, int out_size, void* d_ws, size_t ws_size,
                              hipStream_t stream) {
  (void)in_sizes; (void)n_in; (void)ws_size;
  const float* x        = (const float*)d_in[0];
  const float* conv_w   = (const float*)d_in[1];
  const float* q_w      = (const float*)d_in[2];
  const float* k_w      = (const float*)d_in[3];
  const float* v_w      = (const float*)d_in[4];
  const float* mlp_w1   = (const float*)d_in[5];
  const float* mlp_b1   = (const float*)d_in[6];
  const float* mlp_w2   = (const float*)d_in[7];
  const float* mlp_b2   = (const float*)d_in[8];
  const float* ln_in_g  = (const float*)d_in[9];
  const float* ln_in_b  = (const float*)d_in[10];
  const float* ln_out_g = (const float*)d_in[11];
  const float* ln_out_b = (const float*)d_in[12];
  const float* ln_attn_g= (const float*)d_in[13];
  const float* ln_attn_b= (const float*)d_in[14];
  const float* ln_mlp_g = (const float*)d_in[15];
  const float* ln_mlp_b = (const float*)d_in[16];
  const float* tau      = (const float*)d_in[17];
  const float* rpb      = (const float*)d_in[18];
  const int*   qidx     = (const int*)d_in[20];

  float* out = (float*)d_out;
  float* aups  = out + 1204224;       // 8*784*192
  float* adown = out + 20873216;      // + 8*3136*784

  float* ws   = (float*)d_ws;
  float* wct  = ws;                   // 165888
  float* wkvT = wct + 165888;         // 27648
  float* qwT  = wkvT + 27648;         // 18432
  float* w1T  = qwT + 18432;          // 73728
  float* w2T  = w1T + 73728;          // 73728
  float* xn   = w2T + 73728;          // 25088*96
  float* kvb  = xn + (size_t)TOK_IN*DIN;    // 25088*288
  float* xo   = kvb + (size_t)TOK_IN*288;   // 6272*192
  float* xqn  = xo + (size_t)TOK_OUT*DOUT;  // 6272*192
  float* qb   = xqn + (size_t)TOK_OUT*DOUT; // 6272*96
  float* cs   = qb + (size_t)TOK_OUT*DIN;   // 6272

  // zero the dense outputs (a_ups / a_down are sparse; x_out fully overwritten)
  hipMemsetAsync(d_out, 0, (size_t)out_size * sizeof(float), stream);

  k_tr<<<1404, 256, 0, stream>>>(conv_w, k_w, v_w, q_w, mlp_w1, mlp_w2,
                                 wct, wkvT, qwT, w1T, w2T);
  k_conv<<<dim3(28, 8), 192, 0, stream>>>(x, wct, xo);
  k_ln<<<TOK_OUT, 64, 0, stream>>>(xo, xo, ln_out_g, ln_out_b, DOUT);   // x_out = LN(seed)
  k_ln<<<TOK_IN, 64, 0, stream>>>(x, xn, ln_in_g, ln_in_b, DIN);        // xn = LN(x)
  k_kv<<<TOK_IN/32, 256, 0, stream>>>(xn, wkvT, kvb);

  for (int it = 0; it < 3; it++) {
    k_ln<<<TOK_OUT, 64, 0, stream>>>(xo, xqn, ln_out_g, ln_out_b, DOUT);
    k_q<<<TOK_OUT/32, 256, 0, stream>>>(xqn, qwT, qb);
    hipMemsetAsync(cs, 0, TOK_OUT * sizeof(float), stream);
    k_attn1<<<TOK_IN/4, 256, 0, stream>>>(kvb, qb, tau, rpb, qidx, aups, cs);
    k_upd<<<dim3(14, 14, NB), 192, 0, stream>>>(aups, cs, kvb, xo, ln_attn_g, ln_attn_b);
    k_mlp<<<TOK_OUT/32, 256, 0, stream>>>(xo, w1T, mlp_b1, w2T, mlp_b2,
                                          ln_mlp_g, ln_mlp_b, out, it == 2);
  }
  k_attn2<<<TOK_IN/256, 256, 0, stream>>>(aups, cs, adown);
}

// Round 2
// 1059.387 us; speedup vs baseline: 2.5849x; 2.5849x over previous
//
#include <hip/hip_runtime.h>
#include <hip/hip_bf16.h>
#include <math.h>

#define NB 8
#define NIN 3136
#define NOUT 784
#define DIN 96
#define DOUT 192
#define HID 384
#define TOK_IN (NB*NIN)    // 25088
#define TOK_OUT (NB*NOUT)  // 6272

// ---------------- generic LayerNorm over last dim (D<=192), one row per block (64 thr)
__global__ __launch_bounds__(64) void k_ln(const float* __restrict__ in, float* __restrict__ out,
                                           const float* __restrict__ g, const float* __restrict__ bb,
                                           int D) {
  int row = blockIdx.x;
  const float* ip = in + (size_t)row * D;
  float* op = out + (size_t)row * D;
  int t = threadIdx.x;
  float v0 = 0.f, v1 = 0.f, v2 = 0.f, s = 0.f, sq = 0.f;
  if (t < D)       { v0 = ip[t];       s += v0; sq += v0*v0; }
  if (t + 64 < D)  { v1 = ip[t+64];    s += v1; sq += v1*v1; }
  if (t + 128 < D) { v2 = ip[t+128];   s += v2; sq += v2*v2; }
  #pragma unroll
  for (int off = 32; off; off >>= 1) { s += __shfl_xor(s, off); sq += __shfl_xor(sq, off); }
  float mu = s / (float)D;
  float var = sq / (float)D - mu*mu;
  float rs = rsqrtf(var + 1e-5f);
  if (t < D)       op[t]     = (v0-mu)*rs*g[t]     + bb[t];
  if (t + 64 < D)  op[t+64]  = (v1-mu)*rs*g[t+64]  + bb[t+64];
  if (t + 128 < D) op[t+128] = (v2-mu)*rs*g[t+128] + bb[t+128];
}

// ---------------- weight transposes (once per launch)
// wct layout: [kh][kw][ci4][co][4]  (float4 per (co, ci-quad))
__global__ void k_tr(const float* __restrict__ cw, const float* __restrict__ kw,
                     const float* __restrict__ vw, const float* __restrict__ qw,
                     const float* __restrict__ w1, const float* __restrict__ w2,
                     float* __restrict__ wct, float* __restrict__ wkvT, float* __restrict__ qwT,
                     float* __restrict__ w1T, float* __restrict__ w2T) {
  int i = blockIdx.x * 256 + threadIdx.x;
  if (i < 165888) {                               // wct[kh][kw][ci4][co][q]
    int q = i & 3; int t1 = i >> 2;
    int co = t1 % 192; int t2 = t1 / 192;
    int ci4 = t2 % 24; int t3 = t2 / 24;
    int kwi = t3 % 3; int kh = t3 / 3;
    wct[i] = cw[((co*96 + ci4*4 + q)*3 + kh)*3 + kwi];
  } else if (i < 165888 + 27648) {                // wkvT[e][288] : k|v
    int j = i - 165888; int o = j % 288; int e = j / 288;
    wkvT[j] = (o < 96) ? kw[o*96 + e] : vw[(o-96)*96 + e];
  } else if (i < 165888 + 27648 + 18432) {        // qwT[e][96]
    int j = i - 165888 - 27648; int o = j % 96; int e = j / 96;
    qwT[j] = qw[o*192 + e];
  } else if (i < 165888 + 27648 + 18432 + 73728) {// w1T[e][384]
    int j = i - 165888 - 27648 - 18432; int hh = j % 384; int e = j / 384;
    w1T[j] = w1[hh*192 + e];
  } else if (i < 165888 + 27648 + 18432 + 73728 + 73728) { // w2T[h][192]
    int j = i - 165888 - 27648 - 18432 - 73728; int o = j % 192; int h = j / 192;
    w2T[j] = w2[o*384 + h];
  }
}

// ---------------- strided 3x3 conv seed, LDS-staged implicit GEMM.
// block = (ho, b, co_half), 448 thr = 14 groups x 32 lanes.
// group tg handles wo in {2tg, 2tg+1}; lane ol handles co = half*96 + ol + 32j, j<3.
__global__ __launch_bounds__(448) void k_conv(const float* __restrict__ x,
                                              const float* __restrict__ wct,
                                              float* __restrict__ seed) {
  __shared__ float xs[3][58][96];   // [kh][col+1][ci], zero-padded borders
  int ho = blockIdx.x, b = blockIdx.y, half = blockIdx.z;
  int t = threadIdx.x;
  for (int idx = t; idx < 3*58*96; idx += 448) {
    int ci = idx % 96; int rest = idx / 96;
    int col = rest % 58; int kh = rest / 58;
    int h = 2*ho - 1 + kh;
    int c = col - 1;
    float v = 0.f;
    if (h >= 0 && h < 56 && c >= 0 && c < 56)
      v = x[((size_t)b*NIN + h*56 + c)*DIN + ci];
    xs[kh][col][ci] = v;
  }
  __syncthreads();
  int ol = t & 31, tg = t >> 5;       // tg in [0,14)
  int wo0 = tg * 2;
  int co = half*96 + ol;
  float acc[2][3];
  #pragma unroll
  for (int i = 0; i < 2; i++) { acc[i][0]=0.f; acc[i][1]=0.f; acc[i][2]=0.f; }
  #pragma unroll
  for (int kh = 0; kh < 3; kh++) {
    #pragma unroll
    for (int kwv = 0; kwv < 3; kwv++) {
      #pragma unroll 4
      for (int ci4 = 0; ci4 < 24; ci4++) {
        const float4* wp = (const float4*)wct + (((kh*3 + kwv)*24 + ci4)*192 + co);
        float4 w0 = wp[0], w1 = wp[32], w2 = wp[64];
        float4 x0 = *(const float4*)&xs[kh][2*wo0 + kwv][ci4*4];
        float4 x1 = *(const float4*)&xs[kh][2*wo0 + 2 + kwv][ci4*4];
        acc[0][0] += x0.x*w0.x + x0.y*w0.y + x0.z*w0.z + x0.w*w0.w;
        acc[0][1] += x0.x*w1.x + x0.y*w1.y + x0.z*w1.z + x0.w*w1.w;
        acc[0][2] += x0.x*w2.x + x0.y*w2.y + x0.z*w2.z + x0.w*w2.w;
        acc[1][0] += x1.x*w0.x + x1.y*w0.y + x1.z*w0.z + x1.w*w0.w;
        acc[1][1] += x1.x*w1.x + x1.y*w1.y + x1.z*w1.z + x1.w*w1.w;
        acc[1][2] += x1.x*w2.x + x1.y*w2.y + x1.z*w2.z + x1.w*w2.w;
      }
    }
  }
  #pragma unroll
  for (int i = 0; i < 2; i++)
    #pragma unroll
    for (int j = 0; j < 3; j++)
      seed[((size_t)b*NOUT + ho*28 + wo0 + i)*DOUT + co + 32*j] = acc[i][j];
}

// ---------------- kv = xn @ [k_w|v_w]^T. block=32 tokens, 256 thr (32 olane x 8 tg), TM=4 TN=9
__global__ __launch_bounds__(256) void k_kv(const float* __restrict__ xn,
                                            const float* __restrict__ wkvT,
                                            float* __restrict__ kvb) {
  __shared__ float xt[32][98];
  int tok0 = blockIdx.x * 32;
  int t = threadIdx.x;
  for (int i = t; i < 32*DIN; i += 256) {
    int tok = i / DIN, e = i % DIN;
    xt[tok][e] = xn[(size_t)(tok0 + tok)*DIN + e];
  }
  __syncthreads();
  int ol = t & 31, tg = t >> 5;
  float acc[4][9];
  #pragma unroll
  for (int i = 0; i < 4; i++)
    #pragma unroll
    for (int j = 0; j < 9; j++) acc[i][j] = 0.f;
  for (int e = 0; e < DIN; e++) {
    float x0 = xt[tg*4+0][e], x1 = xt[tg*4+1][e], x2 = xt[tg*4+2][e], x3 = xt[tg*4+3][e];
    const float* wp = wkvT + (size_t)e*288 + ol;
    #pragma unroll
    for (int j = 0; j < 9; j++) {
      float wv = wp[32*j];
      acc[0][j] += x0*wv; acc[1][j] += x1*wv; acc[2][j] += x2*wv; acc[3][j] += x3*wv;
    }
  }
  #pragma unroll
  for (int i = 0; i < 4; i++)
    #pragma unroll
    for (int j = 0; j < 9; j++)
      kvb[(size_t)(tok0 + tg*4 + i)*288 + ol + 32*j] = acc[i][j];
}

// ---------------- q = LN(x_out) @ q_w^T. block=32 tokens, TM=4 TN=3
__global__ __launch_bounds__(256) void k_q(const float* __restrict__ xqn,
                                           const float* __restrict__ qwT,
                                           float* __restrict__ qb) {
  __shared__ float xt[32][194];
  int tok0 = blockIdx.x * 32;
  int t = threadIdx.x;
  for (int i = t; i < 32*DOUT; i += 256) {
    int tok = i / DOUT, e = i % DOUT;
    xt[tok][e] = xqn[(size_t)(tok0 + tok)*DOUT + e];
  }
  __syncthreads();
  int ol = t & 31, tg = t >> 5;
  float acc[4][3];
  #pragma unroll
  for (int i = 0; i < 4; i++) { acc[i][0]=0.f; acc[i][1]=0.f; acc[i][2]=0.f; }
  for (int e = 0; e < DOUT; e++) {
    float x0 = xt[tg*4+0][e], x1 = xt[tg*4+1][e], x2 = xt[tg*4+2][e], x3 = xt[tg*4+3][e];
    const float* wp = qwT + (size_t)e*DIN + ol;
    #pragma unroll
    for (int j = 0; j < 3; j++) {
      float wv = wp[32*j];
      acc[0][j] += x0*wv; acc[1][j] += x1*wv; acc[2][j] += x2*wv; acc[3][j] += x3*wv;
    }
  }
  #pragma unroll
  for (int i = 0; i < 4; i++)
    #pragma unroll
    for (int j = 0; j < 3; j++)
      qb[(size_t)(tok0 + tg*4 + i)*DIN + ol + 32*j] = acc[i][j];
}

// ---------------- window helper: 9 candidate slots + duplicate mask (all constant-indexed)
__device__ __forceinline__ void window9(int n, int* ms, bool* dup) {
  int r = n / 56, c = n % 56;
  int rb = r >> 1, cb = c >> 1;
  #pragma unroll
  for (int j = 0; j < 9; j++) {
    int ro = rb + (j/3) - 1; ro = ro < 0 ? 0 : (ro > 27 ? 27 : ro);
    int co = cb + (j%3) - 1; co = co < 0 ? 0 : (co > 27 ? 27 : co);
    ms[j] = ro*28 + co;
  }
  #pragma unroll
  for (int j = 0; j < 9; j++) {
    bool d = false;
    #pragma unroll
    for (int i = 0; i < j; i++) d = d || (ms[i] == ms[j]);
    dup[j] = d;
  }
}

// ---------------- sparse logits + softmax + a_ups + colsum. one wave per (b,n)
__global__ __launch_bounds__(256) void k_attn1(const float* __restrict__ kvb,
                                               const float* __restrict__ qb,
                                               const float* __restrict__ tau,
                                               const float* __restrict__ rpb,
                                               const int* __restrict__ qidx,
                                               float* __restrict__ aups,
                                               float* __restrict__ colsum) {
  int wid = blockIdx.x * 4 + (threadIdx.x >> 6);
  int l = threadIdx.x & 63;
  int b = wid / NIN, n = wid % NIN;
  int ms[9]; bool dup[9];
  window9(n, ms, dup);
  const float* kp = kvb + (size_t)wid * 288;
  float k0 = kp[l];
  float k1 = (l < 32) ? kp[64 + l] : 0.0f;
  float et = expf(tau[0]);
  float lg[9];
  #pragma unroll
  for (int j = 0; j < 9; j++) {
    float d = -1e30f;
    if (!dup[j]) {
      const float* qp = qb + (size_t)(b*NOUT + ms[j]) * DIN;
      float p = k0 * qp[l];
      if (l < 32) p += k1 * qp[64 + l];
      #pragma unroll
      for (int off = 32; off; off >>= 1) p += __shfl_xor(p, off);
      d = p * et + rpb[qidx[(size_t)n*NOUT + ms[j]]];
    }
    lg[j] = d;
  }
  float mx = lg[0];
  #pragma unroll
  for (int j = 1; j < 9; j++) mx = fmaxf(mx, lg[j]);
  float s = 0.f, ex[9];
  #pragma unroll
  for (int j = 0; j < 9; j++) { ex[j] = dup[j] ? 0.f : expf(lg[j] - mx); s += ex[j]; }
  float inv = 1.0f / s;
  #pragma unroll
  for (int j = 0; j < 9; j++) {
    if (l == j && !dup[j]) {
      float a = ex[j] * inv;
      aups[(size_t)wid*NOUT + ms[j]] = a;
      atomicAdd(&colsum[b*NOUT + ms[j]], a);
    }
  }
}

// ---------------- a_down (final iteration only): thread per (b,n)
__global__ __launch_bounds__(256) void k_attn2(const float* __restrict__ aups,
                                               const float* __restrict__ colsum,
                                               float* __restrict__ adown) {
  int id = blockIdx.x * 256 + threadIdx.x;
  int b = id / NIN, n = id % NIN;
  int ms[9]; bool dup[9];
  window9(n, ms, dup);
  #pragma unroll
  for (int j = 0; j < 9; j++) {
    if (!dup[j]) {
      size_t idx = (size_t)id*NOUT + ms[j];
      adown[idx] = aups[idx] / (colsum[b*NOUT + ms[j]] + 1e-8f);
    }
  }
}

// ---------------- updates gather + LN + residual. block = (b, 2x2 slot tile), 192 thr
__global__ __launch_bounds__(192) void k_upd(const float* __restrict__ aups,
                                             const float* __restrict__ colsum,
                                             const float* __restrict__ kvb,
                                             float* __restrict__ xout,
                                             const float* __restrict__ g,
                                             const float* __restrict__ bb) {
  __shared__ float avals[4][64];
  __shared__ float red[4][3][2];
  __shared__ float bc[4][2];
  int b = blockIdx.z;
  int ro0 = blockIdx.y*2, co0 = blockIdx.x*2;
  int r0 = 2*ro0 - 2; if (r0 < 0) r0 = 0;
  int r1 = 2*ro0 + 5; if (r1 > 55) r1 = 55;
  int c0 = 2*co0 - 2; if (c0 < 0) c0 = 0;
  int c1 = 2*co0 + 5; if (c1 > 55) c1 = 55;
  int nr = r1 - r0 + 1, nc = c1 - c0 + 1, cnt = nr*nc;
  int t = threadIdx.x;
  int m0 = ro0*28 + co0, m1 = m0+1, m2 = m0+28, m3 = m0+29;
  if (t < cnt) {
    int ri = t / nc, ci = t % nc;
    int n = (r0 + ri)*56 + (c0 + ci);
    const float* ap = aups + ((size_t)b*NIN + n)*NOUT;
    avals[0][t] = ap[m0]; avals[1][t] = ap[m1];
    avals[2][t] = ap[m2]; avals[3][t] = ap[m3];
  }
  __syncthreads();
  float a0=0.f, a1=0.f, a2=0.f, a3=0.f;
  int i = 0;
  for (int ri = 0; ri < nr; ri++) {
    int nbase = (r0 + ri)*56 + c0;
    for (int ci = 0; ci < nc; ci++, i++) {
      float vv = kvb[((size_t)b*NIN + nbase + ci)*288 + 96 + t];
      a0 += avals[0][i]*vv; a1 += avals[1][i]*vv;
      a2 += avals[2][i]*vv; a3 += avals[3][i]*vv;
    }
  }
  a0 *= 1.0f/(colsum[b*NOUT+m0]+1e-8f);
  a1 *= 1.0f/(colsum[b*NOUT+m1]+1e-8f);
  a2 *= 1.0f/(colsum[b*NOUT+m2]+1e-8f);
  a3 *= 1.0f/(colsum[b*NOUT+m3]+1e-8f);
  float s0=a0,s1=a1,s2=a2,s3=a3, q0=a0*a0,q1=a1*a1,q2=a2*a2,q3=a3*a3;
  #pragma unroll
  for (int off = 32; off; off >>= 1) {
    s0 += __shfl_xor(s0, off); q0 += __shfl_xor(q0, off);
    s1 += __shfl_xor(s1, off); q1 += __shfl_xor(q1, off);
    s2 += __shfl_xor(s2, off); q2 += __shfl_xor(q2, off);
    s3 += __shfl_xor(s3, off); q3 += __shfl_xor(q3, off);
  }
  int w = t >> 6, l = t & 63;
  if (l == 0) {
    red[0][w][0]=s0; red[0][w][1]=q0;
    red[1][w][0]=s1; red[1][w][1]=q1;
    red[2][w][0]=s2; red[2][w][1]=q2;
    red[3][w][0]=s3; red[3][w][1]=q3;
  }
  __syncthreads();
  if (t < 4) {
    float S = red[t][0][0]+red[t][1][0]+red[t][2][0];
    float Q = red[t][0][1]+red[t][1][1]+red[t][2][1];
    float mu = S * (1.0f/192.0f);
    float var = Q * (1.0f/192.0f) - mu*mu;
    bc[t][0] = mu; bc[t][1] = rsqrtf(var + 1e-5f);
  }
  __syncthreads();
  float gt = g[t], bt = bb[t];
  xout[((size_t)b*NOUT+m0)*DOUT + t] += (a0-bc[0][0])*bc[0][1]*gt + bt;
  xout[((size_t)b*NOUT+m1)*DOUT + t] += (a1-bc[1][0])*bc[1][1]*gt + bt;
  xout[((size_t)b*NOUT+m2)*DOUT + t] += (a2-bc[2][0])*bc[2][1]*gt + bt;
  xout[((size_t)b*NOUT+m3)*DOUT + t] += (a3-bc[3][0])*bc[3][1]*gt + bt;
}

// ---------------- MLP + LN + residual. block = 32 tokens, 256 thr
__global__ __launch_bounds__(256) void k_mlp(float* __restrict__ xout,
                                             const float* __restrict__ w1T, const float* __restrict__ b1,
                                             const float* __restrict__ w2T, const float* __restrict__ b2,
                                             const float* __restrict__ g, const float* __restrict__ bb,
                                             float* __restrict__ dout, int write_out) {
  __shared__ float xt[32][194];
  __shared__ float ht[32][386];
  int tok0 = blockIdx.x * 32;
  int t = threadIdx.x;
  for (int idx = t; idx < 32*DOUT; idx += 256) {
    int tok = idx / DOUT, e = idx % DOUT;
    xt[tok][e] = xout[(size_t)(tok0 + tok)*DOUT + e];
  }
  __syncthreads();
  int ol = t & 31, tg = t >> 5;
  float acc[4][12];
  #pragma unroll
  for (int i = 0; i < 4; i++)
    #pragma unroll
    for (int j = 0; j < 12; j++) acc[i][j] = 0.f;
  for (int e = 0; e < DOUT; e++) {
    float x0 = xt[tg*4+0][e], x1 = xt[tg*4+1][e], x2 = xt[tg*4+2][e], x3 = xt[tg*4+3][e];
    const float* wp = w1T + (size_t)e*HID + ol;
    #pragma unroll
    for (int j = 0; j < 12; j++) {
      float wv = wp[32*j];
      acc[0][j] += x0*wv; acc[1][j] += x1*wv; acc[2][j] += x2*wv; acc[3][j] += x3*wv;
    }
  }
  #pragma unroll
  for (int j = 0; j < 12; j++) {
    int hh = ol + 32*j;
    float bv = b1[hh];
    #pragma unroll
    for (int i = 0; i < 4; i++) {
      float v = acc[i][j] + bv;
      v = 0.5f*v*(1.0f + erff(v*0.70710678118f));
      ht[tg*4+i][hh] = v;
    }
  }
  __syncthreads();
  float o2[4][6];
  #pragma unroll
  for (int i = 0; i < 4; i++)
    #pragma unroll
    for (int j = 0; j < 6; j++) o2[i][j] = 0.f;
  for (int h = 0; h < HID; h++) {
    float x0 = ht[tg*4+0][h], x1 = ht[tg*4+1][h], x2 = ht[tg*4+2][h], x3 = ht[tg*4+3][h];
    const float* wp = w2T + (size_t)h*DOUT + ol;
    #pragma unroll
    for (int j = 0; j < 6; j++) {
      float wv = wp[32*j];
      o2[0][j] += x0*wv; o2[1][j] += x1*wv; o2[2][j] += x2*wv; o2[3][j] += x3*wv;
    }
  }
  __syncthreads();
  float (*ot)[194] = (float(*)[194])ht;   // reuse h LDS for the out tile
  #pragma unroll
  for (int j = 0; j < 6; j++) {
    int o = ol + 32*j;
    float bv = b2[o];
    #pragma unroll
    for (int i = 0; i < 4; i++) ot[tg*4+i][o] = o2[i][j] + bv;
  }
  __syncthreads();
  int tok = t >> 3, l8 = t & 7;
  float s = 0.f, sq = 0.f;
  for (int e = l8; e < DOUT; e += 8) { float v = ot[tok][e]; s += v; sq += v*v; }
  #pragma unroll
  for (int off = 4; off; off >>= 1) { s += __shfl_xor(s, off, 8); sq += __shfl_xor(sq, off, 8); }
  float mu = s * (1.f/192.f);
  float var = sq * (1.f/192.f) - mu*mu;
  float rs = rsqrtf(var + 1e-5f);
  for (int e = l8; e < DOUT; e += 8) {
    float v = (ot[tok][e] - mu)*rs*g[e] + bb[e];
    float nx = xt[tok][e] + v;
    size_t gi = (size_t)(tok0 + tok)*DOUT + e;
    xout[gi] = nx;
    if (write_out) dout[gi] = nx;
  }
}

extern "C" void kernel_launch(void* const* d_in, const int* in_sizes, int n_in,
                              void* d_out, int out_size, void* d_ws, size_t ws_size,
                              hipStream_t stream) {
  (void)in_sizes; (void)n_in; (void)ws_size;
  const float* x        = (const float*)d_in[0];
  const float* conv_w   = (const float*)d_in[1];
  const float* q_w      = (const float*)d_in[2];
  const float* k_w      = (const float*)d_in[3];
  const float* v_w      = (const float*)d_in[4];
  const float* mlp_w1   = (const float*)d_in[5];
  const float* mlp_b1   = (const float*)d_in[6];
  const float* mlp_w2   = (const float*)d_in[7];
  const float* mlp_b2   = (const float*)d_in[8];
  const float* ln_in_g  = (const float*)d_in[9];
  const float* ln_in_b  = (const float*)d_in[10];
  const float* ln_out_g = (const float*)d_in[11];
  const float* ln_out_b = (const float*)d_in[12];
  const float* ln_attn_g= (const float*)d_in[13];
  const float* ln_attn_b= (const float*)d_in[14];
  const float* ln_mlp_g = (const float*)d_in[15];
  const float* ln_mlp_b = (const float*)d_in[16];
  const float* tau      = (const float*)d_in[17];
  const float* rpb      = (const float*)d_in[18];
  const int*   qidx     = (const int*)d_in[20];

  float* out = (float*)d_out;
  float* aups  = out + 1204224;       // 8*784*192
  float* adown = out + 20873216;      // + 8*3136*784

  float* ws   = (float*)d_ws;
  float* wct  = ws;                   // 165888
  float* wkvT = wct + 165888;         // 27648
  float* qwT  = wkvT + 27648;         // 18432
  float* w1T  = qwT + 18432;          // 73728
  float* w2T  = w1T + 73728;          // 73728
  float* xn   = w2T + 73728;          // 25088*96
  float* kvb  = xn + (size_t)TOK_IN*DIN;    // 25088*288
  float* xo   = kvb + (size_t)TOK_IN*288;   // 6272*192
  float* xqn  = xo + (size_t)TOK_OUT*DOUT;  // 6272*192
  float* qb   = xqn + (size_t)TOK_OUT*DOUT; // 6272*96
  float* cs   = qb + (size_t)TOK_OUT*DIN;   // 6272

  // zero the dense outputs (a_ups / a_down are sparse; x_out fully overwritten)
  hipMemsetAsync(d_out, 0, (size_t)out_size * sizeof(float), stream);

  k_tr<<<1404, 256, 0, stream>>>(conv_w, k_w, v_w, q_w, mlp_w1, mlp_w2,
                                 wct, wkvT, qwT, w1T, w2T);
  k_conv<<<dim3(28, 8, 2), 448, 0, stream>>>(x, wct, xo);
  k_ln<<<TOK_OUT, 64, 0, stream>>>(xo, xo, ln_out_g, ln_out_b, DOUT);   // x_out = LN(seed)
  k_ln<<<TOK_IN, 64, 0, stream>>>(x, xn, ln_in_g, ln_in_b, DIN);        // xn = LN(x)
  k_kv<<<TOK_IN/32, 256, 0, stream>>>(xn, wkvT, kvb);

  for (int it = 0; it < 3; it++) {
    k_ln<<<TOK_OUT, 64, 0, stream>>>(xo, xqn, ln_out_g, ln_out_b, DOUT);
    k_q<<<TOK_OUT/32, 256, 0, stream>>>(xqn, qwT, qb);
    hipMemsetAsync(cs, 0, TOK_OUT * sizeof(float), stream);
    k_attn1<<<TOK_IN/4, 256, 0, stream>>>(kvb, qb, tau, rpb, qidx, aups, cs);
    k_upd<<<dim3(14, 14, NB), 192, 0, stream>>>(aups, cs, kvb, xo, ln_attn_g, ln_attn_b);
    k_mlp<<<TOK_OUT/32, 256, 0, stream>>>(xo, w1T, mlp_b1, w2T, mlp_b2,
                                          ln_mlp_g, ln_mlp_b, out, it == 2);
  }
  k_attn2<<<TOK_IN/256, 256, 0, stream>>>(aups, cs, adown);
}

// Round 3
// 909.202 us; speedup vs baseline: 3.0119x; 1.1652x over previous
//
#include <hip/hip_runtime.h>
#include <hip/hip_bf16.h>
#include <math.h>

#define NB 8
#define NIN 3136
#define NOUT 784
#define DIN 96
#define DOUT 192
#define HID 384
#define TOK_IN (NB*NIN)    // 25088
#define TOK_OUT (NB*NOUT)  // 6272

// ---------------- generic LayerNorm over last dim (D<=192), one row per block (64 thr)
__global__ __launch_bounds__(64) void k_ln(const float* __restrict__ in, float* __restrict__ out,
                                           const float* __restrict__ g, const float* __restrict__ bb,
                                           int D) {
  int row = blockIdx.x;
  const float* ip = in + (size_t)row * D;
  float* op = out + (size_t)row * D;
  int t = threadIdx.x;
  float v0 = 0.f, v1 = 0.f, v2 = 0.f, s = 0.f, sq = 0.f;
  if (t < D)       { v0 = ip[t];       s += v0; sq += v0*v0; }
  if (t + 64 < D)  { v1 = ip[t+64];    s += v1; sq += v1*v1; }
  if (t + 128 < D) { v2 = ip[t+128];   s += v2; sq += v2*v2; }
  #pragma unroll
  for (int off = 32; off; off >>= 1) { s += __shfl_xor(s, off); sq += __shfl_xor(sq, off); }
  float mu = s / (float)D;
  float var = sq / (float)D - mu*mu;
  float rs = rsqrtf(var + 1e-5f);
  if (t < D)       op[t]     = (v0-mu)*rs*g[t]     + bb[t];
  if (t + 64 < D)  op[t+64]  = (v1-mu)*rs*g[t+64]  + bb[t+64];
  if (t + 128 < D) op[t+128] = (v2-mu)*rs*g[t+128] + bb[t+128];
}

// ---------------- weight transposes (once per launch)
// wct  : [kh][kw][ci4][co][4]
// wkv4 : [e4][288][4]   (e = e4*4+q, cols 0..95 = k_w, 96..287 = v_w)
// qw4  : [e4][96][4]
// w1_4 : [e4][384][4]
// w2_4 : [h4][192][4]
__global__ void k_tr(const float* __restrict__ cw, const float* __restrict__ kw,
                     const float* __restrict__ vw, const float* __restrict__ qw,
                     const float* __restrict__ w1, const float* __restrict__ w2,
                     float* __restrict__ wct, float* __restrict__ wkv4, float* __restrict__ qw4,
                     float* __restrict__ w1_4, float* __restrict__ w2_4) {
  int i = blockIdx.x * 256 + threadIdx.x;
  if (i < 165888) {                               // wct[kh][kw][ci4][co][q]
    int q = i & 3; int t1 = i >> 2;
    int co = t1 % 192; int t2 = t1 / 192;
    int ci4 = t2 % 24; int t3 = t2 / 24;
    int kwi = t3 % 3; int kh = t3 / 3;
    wct[i] = cw[((co*96 + ci4*4 + q)*3 + kh)*3 + kwi];
  } else if (i < 165888 + 27648) {
    int j = i - 165888; int q = j & 3; int rest = j >> 2;
    int o = rest % 288; int e = (rest / 288)*4 + q;
    wkv4[j] = (o < 96) ? kw[o*96 + e] : vw[(o-96)*96 + e];
  } else if (i < 165888 + 27648 + 18432) {
    int j = i - 165888 - 27648; int q = j & 3; int rest = j >> 2;
    int o = rest % 96; int e = (rest / 96)*4 + q;
    qw4[j] = qw[o*192 + e];
  } else if (i < 165888 + 27648 + 18432 + 73728) {
    int j = i - 165888 - 27648 - 18432; int q = j & 3; int rest = j >> 2;
    int hh = rest % 384; int e = (rest / 384)*4 + q;
    w1_4[j] = w1[hh*192 + e];
  } else if (i < 165888 + 27648 + 18432 + 73728 + 73728) {
    int j = i - 165888 - 27648 - 18432 - 73728; int q = j & 3; int rest = j >> 2;
    int o = rest % 192; int h = (rest / 192)*4 + q;
    w2_4[j] = w2[o*384 + h];
  }
}

// ---------------- strided 3x3 conv seed, LDS-staged implicit GEMM.
__global__ __launch_bounds__(448) void k_conv(const float* __restrict__ x,
                                              const float* __restrict__ wct,
                                              float* __restrict__ seed) {
  __shared__ float xs[3][58][96];
  int ho = blockIdx.x, b = blockIdx.y, half = blockIdx.z;
  int t = threadIdx.x;
  for (int idx = t; idx < 3*58*96; idx += 448) {
    int ci = idx % 96; int rest = idx / 96;
    int col = rest % 58; int kh = rest / 58;
    int h = 2*ho - 1 + kh;
    int c = col - 1;
    float v = 0.f;
    if (h >= 0 && h < 56 && c >= 0 && c < 56)
      v = x[((size_t)b*NIN + h*56 + c)*DIN + ci];
    xs[kh][col][ci] = v;
  }
  __syncthreads();
  int ol = t & 31, tg = t >> 5;       // tg in [0,14)
  int wo0 = tg * 2;
  int co = half*96 + ol;
  float acc[2][3];
  #pragma unroll
  for (int i = 0; i < 2; i++) { acc[i][0]=0.f; acc[i][1]=0.f; acc[i][2]=0.f; }
  #pragma unroll
  for (int kh = 0; kh < 3; kh++) {
    #pragma unroll
    for (int kwv = 0; kwv < 3; kwv++) {
      #pragma unroll 4
      for (int ci4 = 0; ci4 < 24; ci4++) {
        const float4* wp = (const float4*)wct + (((kh*3 + kwv)*24 + ci4)*192 + co);
        float4 w0 = wp[0], w1 = wp[32], w2 = wp[64];
        float4 x0 = *(const float4*)&xs[kh][2*wo0 + kwv][ci4*4];
        float4 x1 = *(const float4*)&xs[kh][2*wo0 + 2 + kwv][ci4*4];
        acc[0][0] += x0.x*w0.x + x0.y*w0.y + x0.z*w0.z + x0.w*w0.w;
        acc[0][1] += x0.x*w1.x + x0.y*w1.y + x0.z*w1.z + x0.w*w1.w;
        acc[0][2] += x0.x*w2.x + x0.y*w2.y + x0.z*w2.z + x0.w*w2.w;
        acc[1][0] += x1.x*w0.x + x1.y*w0.y + x1.z*w0.z + x1.w*w0.w;
        acc[1][1] += x1.x*w1.x + x1.y*w1.y + x1.z*w1.z + x1.w*w1.w;
        acc[1][2] += x1.x*w2.x + x1.y*w2.y + x1.z*w2.z + x1.w*w2.w;
      }
    }
  }
  #pragma unroll
  for (int i = 0; i < 2; i++)
    #pragma unroll
    for (int j = 0; j < 3; j++)
      seed[((size_t)b*NOUT + ho*28 + wo0 + i)*DOUT + co + 32*j] = acc[i][j];
}

// ---------------- kv = xn @ [k_w|v_w]^T. 32 tokens/block, float4 weight fragments.
__global__ __launch_bounds__(256) void k_kv(const float* __restrict__ xn,
                                            const float* __restrict__ wkv4,
                                            float* __restrict__ kvb) {
  __shared__ float xt[32][100];   // padded to mult-of-4 floats
  int tok0 = blockIdx.x * 32;
  int t = threadIdx.x;
  for (int i = t; i < 32*DIN; i += 256) {
    int tok = i / DIN, e = i % DIN;
    xt[tok][e] = xn[(size_t)(tok0 + tok)*DIN + e];
  }
  __syncthreads();
  int ol = t & 31, tg = t >> 5;
  float acc[4][9];
  #pragma unroll
  for (int i = 0; i < 4; i++)
    #pragma unroll
    for (int j = 0; j < 9; j++) acc[i][j] = 0.f;
  const float4* wq = (const float4*)wkv4;
  for (int e4 = 0; e4 < 24; e4++) {
    float4 w[9];
    #pragma unroll
    for (int j = 0; j < 9; j++) w[j] = wq[(size_t)e4*288 + ol + 32*j];
    #pragma unroll
    for (int i = 0; i < 4; i++) {
      float4 xv = *(const float4*)&xt[tg*4+i][e4*4];
      #pragma unroll
      for (int j = 0; j < 9; j++)
        acc[i][j] += xv.x*w[j].x + xv.y*w[j].y + xv.z*w[j].z + xv.w*w[j].w;
    }
  }
  #pragma unroll
  for (int i = 0; i < 4; i++)
    #pragma unroll
    for (int j = 0; j < 9; j++)
      kvb[(size_t)(tok0 + tg*4 + i)*288 + ol + 32*j] = acc[i][j];
}

// ---------------- q = LN(x_out) @ q_w^T. 16 tokens/block (392 blocks), TM=2 TN=3
__global__ __launch_bounds__(256) void k_q(const float* __restrict__ xqn,
                                           const float* __restrict__ qw4,
                                           float* __restrict__ qb) {
  __shared__ float xt[16][196];
  int tok0 = blockIdx.x * 16;
  int t = threadIdx.x;
  for (int i = t; i < 16*DOUT; i += 256) {
    int tok = i / DOUT, e = i % DOUT;
    xt[tok][e] = xqn[(size_t)(tok0 + tok)*DOUT + e];
  }
  __syncthreads();
  int ol = t & 31, tg = t >> 5;   // tg<8, 2 tokens each
  float acc[2][3];
  #pragma unroll
  for (int i = 0; i < 2; i++) { acc[i][0]=0.f; acc[i][1]=0.f; acc[i][2]=0.f; }
  const float4* wq = (const float4*)qw4;
  for (int e4 = 0; e4 < 48; e4++) {
    float4 w[3];
    #pragma unroll
    for (int j = 0; j < 3; j++) w[j] = wq[(size_t)e4*96 + ol + 32*j];
    #pragma unroll
    for (int i = 0; i < 2; i++) {
      float4 xv = *(const float4*)&xt[tg*2+i][e4*4];
      #pragma unroll
      for (int j = 0; j < 3; j++)
        acc[i][j] += xv.x*w[j].x + xv.y*w[j].y + xv.z*w[j].z + xv.w*w[j].w;
    }
  }
  #pragma unroll
  for (int i = 0; i < 2; i++)
    #pragma unroll
    for (int j = 0; j < 3; j++)
      qb[(size_t)(tok0 + tg*2 + i)*DIN + ol + 32*j] = acc[i][j];
}

// ---------------- window helper
__device__ __forceinline__ void window9(int n, int* ms, bool* dup) {
  int r = n / 56, c = n % 56;
  int rb = r >> 1, cb = c >> 1;
  #pragma unroll
  for (int j = 0; j < 9; j++) {
    int ro = rb + (j/3) - 1; ro = ro < 0 ? 0 : (ro > 27 ? 27 : ro);
    int co = cb + (j%3) - 1; co = co < 0 ? 0 : (co > 27 ? 27 : co);
    ms[j] = ro*28 + co;
  }
  #pragma unroll
  for (int j = 0; j < 9; j++) {
    bool d = false;
    #pragma unroll
    for (int i = 0; i < j; i++) d = d || (ms[i] == ms[j]);
    dup[j] = d;
  }
}

// ---------------- sparse logits + softmax + a_ups + colsum. one wave per (b,n)
__global__ __launch_bounds__(256) void k_attn1(const float* __restrict__ kvb,
                                               const float* __restrict__ qb,
                                               const float* __restrict__ tau,
                                               const float* __restrict__ rpb,
                                               const int* __restrict__ qidx,
                                               float* __restrict__ aups,
                                               float* __restrict__ colsum) {
  int wid = blockIdx.x * 4 + (threadIdx.x >> 6);
  int l = threadIdx.x & 63;
  int b = wid / NIN, n = wid % NIN;
  int ms[9]; bool dup[9];
  window9(n, ms, dup);
  const float* kp = kvb + (size_t)wid * 288;
  float k0 = kp[l];
  float k1 = (l < 32) ? kp[64 + l] : 0.0f;
  int l32 = 64 + (l & 31);
  float et = expf(tau[0]);
  // all 9 partials first (loads in flight together), then joint reduce
  float p[9];
  #pragma unroll
  for (int j = 0; j < 9; j++) {
    const float* qp = qb + (size_t)(b*NOUT + ms[j]) * DIN;
    p[j] = k0 * qp[l] + k1 * qp[l32];
  }
  #pragma unroll
  for (int off = 32; off; off >>= 1)
    #pragma unroll
    for (int j = 0; j < 9; j++) p[j] += __shfl_xor(p[j], off);
  float lg[9];
  #pragma unroll
  for (int j = 0; j < 9; j++)
    lg[j] = dup[j] ? -1e30f : p[j] * et + rpb[qidx[(size_t)n*NOUT + ms[j]]];
  float mx = lg[0];
  #pragma unroll
  for (int j = 1; j < 9; j++) mx = fmaxf(mx, lg[j]);
  float s = 0.f, ex[9];
  #pragma unroll
  for (int j = 0; j < 9; j++) { ex[j] = dup[j] ? 0.f : expf(lg[j] - mx); s += ex[j]; }
  float inv = 1.0f / s;
  #pragma unroll
  for (int j = 0; j < 9; j++) {
    if (l == j && !dup[j]) {
      float a = ex[j] * inv;
      aups[(size_t)wid*NOUT + ms[j]] = a;
      atomicAdd(&colsum[b*NOUT + ms[j]], a);
    }
  }
}

// ---------------- a_down (final iteration only): thread per (b,n)
__global__ __launch_bounds__(256) void k_attn2(const float* __restrict__ aups,
                                               const float* __restrict__ colsum,
                                               float* __restrict__ adown) {
  int id = blockIdx.x * 256 + threadIdx.x;
  int b = id / NIN, n = id % NIN;
  int ms[9]; bool dup[9];
  window9(n, ms, dup);
  #pragma unroll
  for (int j = 0; j < 9; j++) {
    if (!dup[j]) {
      size_t idx = (size_t)id*NOUT + ms[j];
      adown[idx] = aups[idx] / (colsum[b*NOUT + ms[j]] + 1e-8f);
    }
  }
}

// ---------------- updates gather + LN + residual. block = (b, 2x2 slot tile), 192 thr
__global__ __launch_bounds__(192) void k_upd(const float* __restrict__ aups,
                                             const float* __restrict__ colsum,
                                             const float* __restrict__ kvb,
                                             float* __restrict__ xout,
                                             const float* __restrict__ g,
                                             const float* __restrict__ bb) {
  __shared__ float avals[4][64];
  __shared__ float red[4][3][2];
  __shared__ float bc[4][2];
  int b = blockIdx.z;
  int ro0 = blockIdx.y*2, co0 = blockIdx.x*2;
  int r0 = 2*ro0 - 2; if (r0 < 0) r0 = 0;
  int r1 = 2*ro0 + 5; if (r1 > 55) r1 = 55;
  int c0 = 2*co0 - 2; if (c0 < 0) c0 = 0;
  int c1 = 2*co0 + 5; if (c1 > 55) c1 = 55;
  int nr = r1 - r0 + 1, nc = c1 - c0 + 1, cnt = nr*nc;
  int t = threadIdx.x;
  int m0 = ro0*28 + co0, m1 = m0+1, m2 = m0+28, m3 = m0+29;
  if (t < cnt) {
    int ri = t / nc, ci = t % nc;
    int n = (r0 + ri)*56 + (c0 + ci);
    const float* ap = aups + ((size_t)b*NIN + n)*NOUT;
    avals[0][t] = ap[m0]; avals[1][t] = ap[m1];
    avals[2][t] = ap[m2]; avals[3][t] = ap[m3];
  }
  __syncthreads();
  float a0=0.f, a1=0.f, a2=0.f, a3=0.f;
  int i = 0;
  for (int ri = 0; ri < nr; ri++) {
    int nbase = (r0 + ri)*56 + c0;
    for (int ci = 0; ci < nc; ci++, i++) {
      float vv = kvb[((size_t)b*NIN + nbase + ci)*288 + 96 + t];
      a0 += avals[0][i]*vv; a1 += avals[1][i]*vv;
      a2 += avals[2][i]*vv; a3 += avals[3][i]*vv;
    }
  }
  a0 *= 1.0f/(colsum[b*NOUT+m0]+1e-8f);
  a1 *= 1.0f/(colsum[b*NOUT+m1]+1e-8f);
  a2 *= 1.0f/(colsum[b*NOUT+m2]+1e-8f);
  a3 *= 1.0f/(colsum[b*NOUT+m3]+1e-8f);
  float s0=a0,s1=a1,s2=a2,s3=a3, q0=a0*a0,q1=a1*a1,q2=a2*a2,q3=a3*a3;
  #pragma unroll
  for (int off = 32; off; off >>= 1) {
    s0 += __shfl_xor(s0, off); q0 += __shfl_xor(q0, off);
    s1 += __shfl_xor(s1, off); q1 += __shfl_xor(q1, off);
    s2 += __shfl_xor(s2, off); q2 += __shfl_xor(q2, off);
    s3 += __shfl_xor(s3, off); q3 += __shfl_xor(q3, off);
  }
  int w = t >> 6, l = t & 63;
  if (l == 0) {
    red[0][w][0]=s0; red[0][w][1]=q0;
    red[1][w][0]=s1; red[1][w][1]=q1;
    red[2][w][0]=s2; red[2][w][1]=q2;
    red[3][w][0]=s3; red[3][w][1]=q3;
  }
  __syncthreads();
  if (t < 4) {
    float S = red[t][0][0]+red[t][1][0]+red[t][2][0];
    float Q = red[t][0][1]+red[t][1][1]+red[t][2][1];
    float mu = S * (1.0f/192.0f);
    float var = Q * (1.0f/192.0f) - mu*mu;
    bc[t][0] = mu; bc[t][1] = rsqrtf(var + 1e-5f);
  }
  __syncthreads();
  float gt = g[t], bt = bb[t];
  xout[((size_t)b*NOUT+m0)*DOUT + t] += (a0-bc[0][0])*bc[0][1]*gt + bt;
  xout[((size_t)b*NOUT+m1)*DOUT + t] += (a1-bc[1][0])*bc[1][1]*gt + bt;
  xout[((size_t)b*NOUT+m2)*DOUT + t] += (a2-bc[2][0])*bc[2][1]*gt + bt;
  xout[((size_t)b*NOUT+m3)*DOUT + t] += (a3-bc[3][0])*bc[3][1]*gt + bt;
}

// ---------------- MLP + LN + residual. 16 tokens/block (392 blocks), 256 thr
__global__ __launch_bounds__(256) void k_mlp(float* __restrict__ xout,
                                             const float* __restrict__ w1_4, const float* __restrict__ b1,
                                             const float* __restrict__ w2_4, const float* __restrict__ b2,
                                             const float* __restrict__ g, const float* __restrict__ bb,
                                             float* __restrict__ dout, int write_out) {
  __shared__ float xt[16][196];
  __shared__ float ht[16][388];
  int tok0 = blockIdx.x * 16;
  int t = threadIdx.x;
  for (int idx = t; idx < 16*DOUT; idx += 256) {
    int tok = idx / DOUT, e = idx % DOUT;
    xt[tok][e] = xout[(size_t)(tok0 + tok)*DOUT + e];
  }
  __syncthreads();
  int ol = t & 31, tg = t >> 5;   // 8 groups x 2 tokens
  float acc[2][12];
  #pragma unroll
  for (int i = 0; i < 2; i++)
    #pragma unroll
    for (int j = 0; j < 12; j++) acc[i][j] = 0.f;
  const float4* w1q = (const float4*)w1_4;
  for (int e4 = 0; e4 < 48; e4++) {
    float4 w[12];
    #pragma unroll
    for (int j = 0; j < 12; j++) w[j] = w1q[(size_t)e4*384 + ol + 32*j];
    #pragma unroll
    for (int i = 0; i < 2; i++) {
      float4 xv = *(const float4*)&xt[tg*2+i][e4*4];
      #pragma unroll
      for (int j = 0; j < 12; j++)
        acc[i][j] += xv.x*w[j].x + xv.y*w[j].y + xv.z*w[j].z + xv.w*w[j].w;
    }
  }
  #pragma unroll
  for (int j = 0; j < 12; j++) {
    int hh = ol + 32*j;
    float bv = b1[hh];
    #pragma unroll
    for (int i = 0; i < 2; i++) {
      float v = acc[i][j] + bv;
      v = 0.5f*v*(1.0f + erff(v*0.70710678118f));
      ht[tg*2+i][hh] = v;
    }
  }
  __syncthreads();
  float o2[2][6];
  #pragma unroll
  for (int i = 0; i < 2; i++)
    #pragma unroll
    for (int j = 0; j < 6; j++) o2[i][j] = 0.f;
  const float4* w2q = (const float4*)w2_4;
  for (int h4 = 0; h4 < 96; h4++) {
    float4 w[6];
    #pragma unroll
    for (int j = 0; j < 6; j++) w[j] = w2q[(size_t)h4*192 + ol + 32*j];
    #pragma unroll
    for (int i = 0; i < 2; i++) {
      float4 hv = *(const float4*)&ht[tg*2+i][h4*4];
      #pragma unroll
      for (int j = 0; j < 6; j++)
        o2[i][j] += hv.x*w[j].x + hv.y*w[j].y + hv.z*w[j].z + hv.w*w[j].w;
    }
  }
  __syncthreads();
  float (*ot)[196] = (float(*)[196])ht;   // reuse h LDS for the out tile
  #pragma unroll
  for (int j = 0; j < 6; j++) {
    int o = ol + 32*j;
    float bv = b2[o];
    #pragma unroll
    for (int i = 0; i < 2; i++) ot[tg*2+i][o] = o2[i][j] + bv;
  }
  __syncthreads();
  int tok = t >> 4, l16 = t & 15;
  float s = 0.f, sq = 0.f;
  for (int e = l16; e < DOUT; e += 16) { float v = ot[tok][e]; s += v; sq += v*v; }
  #pragma unroll
  for (int off = 8; off; off >>= 1) { s += __shfl_xor(s, off, 16); sq += __shfl_xor(sq, off, 16); }
  float mu = s * (1.f/192.f);
  float var = sq * (1.f/192.f) - mu*mu;
  float rs = rsqrtf(var + 1e-5f);
  for (int e = l16; e < DOUT; e += 16) {
    float v = (ot[tok][e] - mu)*rs*g[e] + bb[e];
    float nx = xt[tok][e] + v;
    size_t gi = (size_t)(tok0 + tok)*DOUT + e;
    xout[gi] = nx;
    if (write_out) dout[gi] = nx;
  }
}

extern "C" void kernel_launch(void* const* d_in, const int* in_sizes, int n_in,
                              void* d_out, int out_size, void* d_ws, size_t ws_size,
                              hipStream_t stream) {
  (void)in_sizes; (void)n_in; (void)ws_size;
  const float* x        = (const float*)d_in[0];
  const float* conv_w   = (const float*)d_in[1];
  const float* q_w      = (const float*)d_in[2];
  const float* k_w      = (const float*)d_in[3];
  const float* v_w      = (const float*)d_in[4];
  const float* mlp_w1   = (const float*)d_in[5];
  const float* mlp_b1   = (const float*)d_in[6];
  const float* mlp_w2   = (const float*)d_in[7];
  const float* mlp_b2   = (const float*)d_in[8];
  const float* ln_in_g  = (const float*)d_in[9];
  const float* ln_in_b  = (const float*)d_in[10];
  const float* ln_out_g = (const float*)d_in[11];
  const float* ln_out_b = (const float*)d_in[12];
  const float* ln_attn_g= (const float*)d_in[13];
  const float* ln_attn_b= (const float*)d_in[14];
  const float* ln_mlp_g = (const float*)d_in[15];
  const float* ln_mlp_b = (const float*)d_in[16];
  const float* tau      = (const float*)d_in[17];
  const float* rpb      = (const float*)d_in[18];
  const int*   qidx     = (const int*)d_in[20];

  float* out = (float*)d_out;
  float* aups  = out + 1204224;       // 8*784*192
  float* adown = out + 20873216;      // + 8*3136*784

  float* ws   = (float*)d_ws;
  float* wct  = ws;                   // 165888
  float* wkv4 = wct + 165888;         // 27648
  float* qw4  = wkv4 + 27648;         // 18432
  float* w1_4 = qw4 + 18432;          // 73728
  float* w2_4 = w1_4 + 73728;         // 73728
  float* xn   = w2_4 + 73728;         // 25088*96
  float* kvb  = xn + (size_t)TOK_IN*DIN;    // 25088*288
  float* xo   = kvb + (size_t)TOK_IN*288;   // 6272*192
  float* xqn  = xo + (size_t)TOK_OUT*DOUT;  // 6272*192
  float* qb   = xqn + (size_t)TOK_OUT*DOUT; // 6272*96
  float* cs   = qb + (size_t)TOK_OUT*DIN;   // 6272

  hipMemsetAsync(d_out, 0, (size_t)out_size * sizeof(float), stream);

  k_tr<<<1404, 256, 0, stream>>>(conv_w, k_w, v_w, q_w, mlp_w1, mlp_w2,
                                 wct, wkv4, qw4, w1_4, w2_4);
  k_conv<<<dim3(28, 8, 2), 448, 0, stream>>>(x, wct, xo);
  k_ln<<<TOK_OUT, 64, 0, stream>>>(xo, xo, ln_out_g, ln_out_b, DOUT);   // x_out = LN(seed)
  k_ln<<<TOK_IN, 64, 0, stream>>>(x, xn, ln_in_g, ln_in_b, DIN);        // xn = LN(x)
  k_kv<<<TOK_IN/32, 256, 0, stream>>>(xn, wkv4, kvb);

  for (int it = 0; it < 3; it++) {
    k_ln<<<TOK_OUT, 64, 0, stream>>>(xo, xqn, ln_out_g, ln_out_b, DOUT);
    k_q<<<TOK_OUT/16, 256, 0, stream>>>(xqn, qw4, qb);
    hipMemsetAsync(cs, 0, TOK_OUT * sizeof(float), stream);
    k_attn1<<<TOK_IN/4, 256, 0, stream>>>(kvb, qb, tau, rpb, qidx, aups, cs);
    k_upd<<<dim3(14, 14, NB), 192, 0, stream>>>(aups, cs, kvb, xo, ln_attn_g, ln_attn_b);
    k_mlp<<<TOK_OUT/16, 256, 0, stream>>>(xo, w1_4, mlp_b1, w2_4, mlp_b2,
                                          ln_mlp_g, ln_mlp_b, out, it == 2);
  }
  k_attn2<<<TOK_IN/256, 256, 0, stream>>>(aups, cs, adown);
}